// Round 1
// baseline (49.862 us; speedup 1.0000x reference)
//
#include <hip/hip_runtime.h>

// Problem constants (B=4, S=4096, DM=1024, H=16, HD=64)
#define M_TOTAL 16384
#define DMODEL  1024
#define HDIM    64
#define NHEAD   16

typedef _Float16 half8 __attribute__((ext_vector_type(8)));
typedef float    f32x4 __attribute__((ext_vector_type(4)));

// ---------------------------------------------------------------------------
// Prep: WvT[d][k] = Wv[k][d]  (f16)          [64][1024]
//       WosumT[n][d] = sum_h Wo[h*64+d][n]   [1024][64] (f16)
// 65536 threads, both jobs per thread, reads coalesced on the big side.
// ---------------------------------------------------------------------------
__global__ __launch_bounds__(256) void prep_kernel(const float* __restrict__ Wv,
                                                   const float* __restrict__ Wo,
                                                   _Float16* __restrict__ WvT,
                                                   _Float16* __restrict__ WosumT) {
    const int t = blockIdx.x * 256 + threadIdx.x;   // 0..65535
    {   // WvT: consecutive t -> consecutive d -> coalesced Wv reads
        const int d = t & 63, k = t >> 6;
        WvT[d * DMODEL + k] = (_Float16)Wv[k * HDIM + d];
    }
    {   // WosumT: consecutive t -> consecutive n -> coalesced Wo reads
        const int n = t & 1023, d = t >> 10;
        float s = 0.f;
        #pragma unroll
        for (int h = 0; h < NHEAD; ++h) s += Wo[(h * HDIM + d) * DMODEL + n];
        WosumT[n * HDIM + d] = (_Float16)s;
    }
}

// ---------------------------------------------------------------------------
// Fused main kernel. Block = 16 rows of X, 256 threads (4 waves).
// Phase 1: V[16][64] = X[16][1024] @ Wv + bv   (MFMA, X reg-staged f32->f16)
//          wave w owns output cols [w*16, w*16+16)
// Phase 2: Out[16][1024] = V @ Wosum + bo      (V from LDS, WosumT from L2)
//          wave w owns output cols [w*256, (w+1)*256)
// MFMA 16x16x32 f16 layouts (gfx950):
//   A: lane l holds A[l&15][(l>>4)*8 + j], j=0..7  (16B contiguous in k)
//   B: lane l holds B[(l>>4)*8 + j][l&15]
//   C/D: lane l reg j -> row (l>>4)*4+j, col l&15
// ---------------------------------------------------------------------------
#define XH_STRIDE 136   // 16 rows x 128 k, padded: 272B rows -> 2-way bank alias (free)
#define VH_STRIDE 72    // 16 rows x 64 k, padded: 144B rows -> 2-way bank alias (free)

__global__ __launch_bounds__(256) void mqa_fused(const float* __restrict__ X,
                                                 const float* __restrict__ bv,
                                                 const float* __restrict__ bo,
                                                 const _Float16* __restrict__ WvT,
                                                 const _Float16* __restrict__ WosumT,
                                                 float* __restrict__ Out) {
    __shared__ _Float16 Xh[16 * XH_STRIDE];
    __shared__ _Float16 Vh[16 * VH_STRIDE];

    const int tid = threadIdx.x;
    const int l   = tid & 63;
    const int w   = tid >> 6;     // wave id 0..3
    const int lr  = l & 15;       // fragment row/col
    const int lk  = l >> 4;       // k-group 0..3
    const int m0  = blockIdx.x * 16;

    // ---------------- Phase 1: V = X @ Wv + bv ----------------
    f32x4 acc = {0.f, 0.f, 0.f, 0.f};
    for (int k0 = 0; k0 < DMODEL; k0 += 128) {
        // stage X[16][128] f32 -> f16 into LDS (coalesced float4 loads)
        #pragma unroll
        for (int i = 0; i < 2; ++i) {
            const int f4 = tid + i * 256;       // 0..511
            const int r  = f4 >> 5;             // 32 float4 per row
            const int c4 = f4 & 31;
            const float4 v = *(const float4*)&X[(size_t)(m0 + r) * DMODEL + k0 + c4 * 4];
            union { _Float16 h[4]; unsigned long long u; } p;
            p.h[0] = (_Float16)v.x; p.h[1] = (_Float16)v.y;
            p.h[2] = (_Float16)v.z; p.h[3] = (_Float16)v.w;
            *(unsigned long long*)&Xh[r * XH_STRIDE + c4 * 4] = p.u;
        }
        __syncthreads();
        #pragma unroll
        for (int ks = 0; ks < 4; ++ks) {
            const half8 a = *(const half8*)&Xh[lr * XH_STRIDE + ks * 32 + lk * 8];
            const half8 b = *(const half8*)&WvT[(size_t)(w * 16 + lr) * DMODEL + k0 + ks * 32 + lk * 8];
            acc = __builtin_amdgcn_mfma_f32_16x16x32_f16(a, b, acc, 0, 0, 0);
        }
        __syncthreads();
    }
    // V (+bv) -> LDS as f16
    {
        const float bvv = bv[w * 16 + lr];
        #pragma unroll
        for (int j = 0; j < 4; ++j)
            Vh[(lk * 4 + j) * VH_STRIDE + w * 16 + lr] = (_Float16)(acc[j] + bvv);
    }
    __syncthreads();

    // ---------------- Phase 2: Out = V @ Wosum + bo ----------------
    const half8 a0 = *(const half8*)&Vh[lr * VH_STRIDE + lk * 8];
    const half8 a1 = *(const half8*)&Vh[lr * VH_STRIDE + 32 + lk * 8];
    #pragma unroll 4
    for (int nf = 0; nf < 16; ++nf) {
        const int n0 = w * 256 + nf * 16;
        const half8 b0 = *(const half8*)&WosumT[(size_t)(n0 + lr) * HDIM + lk * 8];
        const half8 b1 = *(const half8*)&WosumT[(size_t)(n0 + lr) * HDIM + 32 + lk * 8];
        f32x4 o = {0.f, 0.f, 0.f, 0.f};
        o = __builtin_amdgcn_mfma_f32_16x16x32_f16(a0, b0, o, 0, 0, 0);
        o = __builtin_amdgcn_mfma_f32_16x16x32_f16(a1, b1, o, 0, 0, 0);
        const float bov = bo[n0 + lr];
        #pragma unroll
        for (int j = 0; j < 4; ++j)
            Out[(size_t)(m0 + lk * 4 + j) * DMODEL + n0 + lr] = o[j] + bov;
    }
}

// ---------------------------------------------------------------------------
extern "C" void kernel_launch(void* const* d_in, const int* in_sizes, int n_in,
                              void* d_out, int out_size, void* d_ws, size_t ws_size,
                              hipStream_t stream) {
    const float* x  = (const float*)d_in[0];
    // d_in[1]=Wq, d_in[2]=bq, d_in[3]=Wk, d_in[4]=bk are mathematically dead:
    // scores are constant over the broadcast axis -> softmax is exactly uniform.
    const float* Wv = (const float*)d_in[5];
    const float* bv = (const float*)d_in[6];
    const float* Wo = (const float*)d_in[7];
    const float* bo = (const float*)d_in[8];

    _Float16* WvT    = (_Float16*)d_ws;                          // 64*1024*2   = 128KB
    _Float16* WosumT = (_Float16*)((char*)d_ws + 64 * 1024 * 2); // 1024*64*2   = 128KB
    float*    out    = (float*)d_out;

    prep_kernel<<<256, 256, 0, stream>>>(Wv, Wo, WvT, WosumT);
    mqa_fused<<<M_TOTAL / 16, 256, 0, stream>>>(x, bv, bo, WvT, WosumT, out);
}